// Round 10
// baseline (216.492 us; speedup 1.0000x reference)
//
#include <hip/hip_runtime.h>
#include <hip/hip_bf16.h>
#include <hip/hip_cooperative_groups.h>

namespace cg = cooperative_groups;

// Problem constants (B, L, H, HS, OUT) = (4, 512, 768, 64, 16)
#define Bc   4
#define Lc   512
#define Hc   768
#define HSc  64
#define OUTc 16
#define Pc   131328   // L*(L+1)/2
#define KC   128      // k-chunk
#define NCH  6        // 768/128
#define XPITCH 776    // x row pitch bf16 (768+8): 2-way banks (free)
#define WPITCH 136    // w row pitch bf16 (128+8)

typedef float floatx4 __attribute__((ext_vector_type(4)));
typedef short bf16x8  __attribute__((ext_vector_type(8)));
typedef float f32x4   __attribute__((ext_vector_type(4)));

__device__ __forceinline__ unsigned short f2bf(float f) {
    unsigned int u = __float_as_uint(f);
    return (unsigned short)((u + 0x7FFFu + ((u >> 16) & 1u)) >> 16);   // RNE
}

// Single cooperative kernel. Grid 512 x 256 thr (2 blocks/CU co-resident;
// LDS 42.2 KB -> occupancy 3/CU, waves 8/CU min — cooperative check passes).
// Phase 1 (blocks 0..255): R9 proj body — MFMA q/k projection + A/Eq/Ek.
// grid.sync()
// Phase 2 (all 512 blocks): R9 pair body over 576 active tiles (t, t+512).
__global__ __launch_bounds__(256) void fused_kernel(
    const float* __restrict__ x,
    const float* __restrict__ Wq, const float* __restrict__ bq,
    const float* __restrict__ Wk, const float* __restrict__ bk,
    const float* __restrict__ Wb, const float* __restrict__ bb,
    float* __restrict__ qws, float* __restrict__ kws,
    float* __restrict__ Aws, float* __restrict__ Eqws, float* __restrict__ Ekws,
    float* __restrict__ out)
{
    __shared__ __align__(16) char lds_raw[16 * XPITCH * 2 + 64 * WPITCH * 2]; // 42240 B

    const int tid = threadIdx.x;
    const int bx  = blockIdx.x;

    // ---------------- Phase 1: projection (blocks 0..255) ----------------
    if (bx < 256) {
        unsigned short* lx = (unsigned short*)lds_raw;                     // [16][XPITCH]
        unsigned short* lw = (unsigned short*)(lds_raw + 16 * XPITCH * 2); // [64][WPITCH]
        float* lc = (float*)(lds_raw + 16 * XPITCH * 2);                   // [16][64] overlays lw

        const int mb   = bx >> 1;
        const int nh   = bx & 1;          // 0: q cols, 1: k cols
        const int m0   = mb * 16;
        const int w    = tid >> 6;
        const int lane = tid & 63;
        const int l15  = lane & 15;
        const int quad = lane >> 4;

        // Stage x tile (16 x 768) -> bf16 LDS, coalesced float4.
        {
            const float4* xg = (const float4*)(x + (size_t)m0 * Hc);   // 3072 float4
            #pragma unroll
            for (int i = 0; i < 12; ++i) {
                const int flat = tid + i * 256;
                const int row  = flat / 192;
                const int c4   = flat - row * 192;
                const float4 v = xg[flat];
                ushort4 o = make_ushort4(f2bf(v.x), f2bf(v.y), f2bf(v.z), f2bf(v.w));
                *(ushort4*)&lx[row * XPITCH + c4 * 4] = o;
            }
        }

        const float* Ws = nh ? Wk : Wq;   // block-uniform
        f32x4 acc = {0.f, 0.f, 0.f, 0.f};

        for (int c = 0; c < NCH; ++c) {
            const int k0 = c * KC;
            if (c) __syncthreads();       // protect lw while previous MFMAs read it
            // Stage W^T half-chunk: lw[n][kk] = Ws[k0+kk][n]; coalesced fp32 loads,
            // pack 2 k per b32 LDS write.
            #pragma unroll 4
            for (int i = 0; i < 16; ++i) {
                const int slot = tid + i * 256;    // 0..4095
                const int n  = slot & 63;
                const int kp = slot >> 6;          // 0..63
                const float w0 = Ws[(k0 + 2 * kp) * HSc + n];
                const float w1 = Ws[(k0 + 2 * kp + 1) * HSc + n];
                const unsigned int pk = (unsigned)f2bf(w0) | ((unsigned)f2bf(w1) << 16);
                *(unsigned int*)&lw[n * WPITCH + 2 * kp] = pk;
            }
            __syncthreads();                       // also covers x-stage for c==0
            #pragma unroll
            for (int m = 0; m < 4; ++m) {
                const int ko = m * 32 + quad * 8;
                const bf16x8 a = *(const bf16x8*)&lx[l15 * XPITCH + k0 + ko];
                const bf16x8 b = *(const bf16x8*)&lw[(w * 16 + l15) * WPITCH + ko];
                acc = __builtin_amdgcn_mfma_f32_16x16x32_bf16(a, b, acc, 0, 0, 0);
            }
        }
        __syncthreads();

        // Epilogue 1: bias + store q/k; stage 16x64 half in lc.
        // D layout: col = l15, row token = quad*4 + r (m89/m91).
        const int gcol = w * 16 + l15;
        const float bias = nh ? bk[gcol] : bq[gcol];
        float* dst = nh ? kws : qws;
        #pragma unroll
        for (int r = 0; r < 4; ++r) {
            const int tl = quad * 4 + r;
            const float v = acc[r] + bias;
            dst[(size_t)(m0 + tl) * HSc + gcol] = v;
            lc[tl * 64 + gcol] = v;
        }
        __syncthreads();

        // Epilogue 2: per-token Wb projections.
        if (nh == 0) {
            #pragma unroll
            for (int i = 0; i < 2; ++i) {
                const int slot = tid + i * 256;
                const int t  = slot >> 5;
                const int cc = slot & 31;
                const float* row = &lc[t * 64];
                const int tok = m0 + t;
                if (cc < 16) {
                    float a = 0.f;
                    #pragma unroll 8
                    for (int h = 0; h < 64; ++h) a += row[h] * Wb[h * OUTc + cc];
                    Aws[(size_t)tok * OUTc + cc] = a;
                } else {
                    const int o = cc - 16;
                    float ev = 0.f;
                    #pragma unroll 8
                    for (int h = 0; h < 64; ++h) ev += row[h] * Wb[(128 + h) * OUTc + o];
                    Eqws[(size_t)tok * OUTc + o] = ev;
                }
            }
        } else {
            const int t = tid >> 4;
            const int o = tid & 15;
            const float* row = &lc[t * 64];
            const int tok = m0 + t;
            float ev = bb[o];
            #pragma unroll 8
            for (int h = 0; h < 64; ++h)
                ev += row[h] * (Wb[(64 + h) * OUTc + o] + Wb[(192 + h) * OUTc + o]);
            Ekws[(size_t)tok * OUTc + o] = ev;
        }
    }

    __threadfence();            // make ws writes visible device-wide
    cg::this_grid().sync();

    // ---------------- Phase 2: pair tiles ----------------
    float* q_tile = (float*)lds_raw;             // [16][64]
    float* A_tile = (float*)(lds_raw + 4096);    // [16][16]

    // Active tiles: (b, i, j) with j >= i>>2; per batch 144, total 576.
    const int cum[9] = {0, 32, 60, 84, 104, 120, 132, 140, 144};

    for (int t = bx; t < 576; t += 512) {
        const int b = t / 144;
        const int r = t - b * 144;
        int g = 0;
        #pragma unroll
        for (int h = 1; h < 8; ++h) if (r >= cum[h]) g = h;
        const int local = r - cum[g];
        const int njg = 8 - g;
        const int iq  = local / njg;            // uniform int div (small)
        const int i = 4 * g + iq;
        const int j = g + (local - iq * njg);
        const int s0 = i * 16;
        const int e0 = j * 64;

        __syncthreads();   // protect LDS from phase-1 / previous tile readers
        {
            const int rr = tid >> 4, c4 = tid & 15;
            ((float4*)(q_tile + rr * 64))[c4] =
                ((const float4*)(qws + ((size_t)b * Lc + s0 + rr) * HSc))[c4];
            if (tid < 64) {
                const int ra = tid >> 2, ca = tid & 3;
                ((float4*)(A_tile + ra * 16))[ca] =
                    ((const float4*)(Aws + ((size_t)b * Lc + s0 + ra) * OUTc))[ca];
            }
        }
        __syncthreads();

        const int gg = tid >> 2;
        const int l  = tid & 3;
        const int e  = e0 + gg;

        const float4* kk = (const float4*)(kws + ((size_t)b * Lc + e) * HSc);
        const float4 kv0 = kk[l];
        const float4 kv1 = kk[4 + l];
        const float4 kv2 = kk[8 + l];
        const float4 kv3 = kk[12 + l];
        const float4 e1 = ((const float4*)(Eqws + ((size_t)b * Lc + e) * OUTc))[l];
        const float4 e2 = ((const float4*)(Ekws + ((size_t)b * Lc + e) * OUTc))[l];
        const float4 ev = make_float4(e1.x + e2.x, e1.y + e2.y, e1.z + e2.z, e1.w + e2.w);

        float* ob = out + (size_t)b * Pc * OUTc;

        #pragma unroll 8
        for (int sl = 0; sl < 16; ++sl) {
            const int s = s0 + sl;
            const float4* qq = (const float4*)(q_tile + sl * 64);
            const float4 qv0 = qq[l];
            const float4 qv1 = qq[4 + l];
            const float4 qv2 = qq[8 + l];
            const float4 qv3 = qq[12 + l];

            float sc = qv0.x * kv0.x + qv0.y * kv0.y + qv0.z * kv0.z + qv0.w * kv0.w
                     + qv1.x * kv1.x + qv1.y * kv1.y + qv1.z * kv1.z + qv1.w * kv1.w
                     + qv2.x * kv2.x + qv2.y * kv2.y + qv2.z * kv2.z + qv2.w * kv2.w
                     + qv3.x * kv3.x + qv3.y * kv3.y + qv3.z * kv3.z + qv3.w * kv3.w;
            sc += __shfl_xor(sc, 1);
            sc += __shfl_xor(sc, 2);

            if (e >= s) {
                const float4 av = ((const float4*)(A_tile + sl * 16))[l];
                const int row = s * (2 * Lc + 1 - s) / 2 + (e - s);
                floatx4 rr;
                rr.x = av.x + ev.x + sc;
                rr.y = av.y + ev.y + sc;
                rr.z = av.z + ev.z + sc;
                rr.w = av.w + ev.w + sc;
                __builtin_nontemporal_store(rr, (floatx4*)(ob + (size_t)row * OUTc) + l);
            }
        }
    }
}

extern "C" void kernel_launch(void* const* d_in, const int* in_sizes, int n_in,
                              void* d_out, int out_size, void* d_ws, size_t ws_size,
                              hipStream_t stream) {
    const float* x  = (const float*)d_in[0];
    const float* Wq = (const float*)d_in[1];
    const float* bq = (const float*)d_in[2];
    const float* Wk = (const float*)d_in[3];
    const float* bk = (const float*)d_in[4];
    const float* Wb = (const float*)d_in[5];
    const float* bb = (const float*)d_in[6];

    float* ws   = (float*)d_ws;
    float* qws  = ws;
    float* kws  = ws + 131072;
    float* Aws  = ws + 262144;
    float* Eqws = ws + 294912;
    float* Ekws = ws + 327680;
    float* outp = (float*)d_out;

    void* args[] = {
        (void*)&x, (void*)&Wq, (void*)&bq, (void*)&Wk, (void*)&bk,
        (void*)&Wb, (void*)&bb, (void*)&qws, (void*)&kws,
        (void*)&Aws, (void*)&Eqws, (void*)&Ekws, (void*)&outp
    };
    hipLaunchCooperativeKernel(fused_kernel, dim3(512), dim3(256),
                               args, 0, stream);
}

// Round 11
// 100.741 us; speedup vs baseline: 2.1490x; 2.1490x over previous
//
#include <hip/hip_runtime.h>
#include <hip/hip_bf16.h>

// Problem constants (B, L, H, HS, OUT) = (4, 512, 768, 64, 16)
#define Bc   4
#define Lc   512
#define Hc   768
#define HSc  64
#define OUTc 16
#define Pc   131328   // L*(L+1)/2
#define NTOK 2048     // B*L

typedef float  floatx4 __attribute__((ext_vector_type(4)));
typedef short  bf16x8  __attribute__((ext_vector_type(8)));   // 8 bf16 in 4 VGPRs
typedef float  f32x4   __attribute__((ext_vector_type(4)));

// ws layout:
//   floats : q@0 [131072], k@131072 [131072], A@262144 [32768], E@294912 [32768]
//   ushorts @ byte offset 327680*4: xbf [2048*768], Wt [128*768]  (Wt = concat(Wq|Wk)^T)

__device__ __forceinline__ unsigned short f2bf(float f) {
    unsigned int u = __float_as_uint(f);
    return (unsigned short)((u + 0x7FFFu + ((u >> 16) & 1u)) >> 16);   // RNE
}

// Prep: blocks 0..511 convert x to bf16; blocks 512..559 build Wt[n][k] bf16.
__global__ __launch_bounds__(256) void prep_kernel(
    const float* __restrict__ x, const float* __restrict__ Wq,
    const float* __restrict__ Wk,
    unsigned short* __restrict__ xbf, unsigned short* __restrict__ Wt)
{
    const int bx  = blockIdx.x;
    const int tid = threadIdx.x;
    if (bx < 512) {
        // 393216 float4 total = 512 blocks * 256 thr * 3
        const float4* xg = (const float4*)x;
        const int base = bx * 768;
        #pragma unroll
        for (int i = 0; i < 3; ++i) {
            const int idx = base + tid + i * 256;
            const float4 v = xg[idx];
            ushort4 o;
            o.x = f2bf(v.x); o.y = f2bf(v.y); o.z = f2bf(v.z); o.w = f2bf(v.w);
            ((ushort4*)xbf)[idx] = o;
        }
    } else {
        // W transpose tile: k rows [k0, k0+16) x 128 n -> Wt[n][k]
        const int k0 = (bx - 512) * 16;
        __shared__ unsigned short T[128][16];
        const int c  = tid & 127;           // n col
        const int kg = tid >> 7;            // 0..1
        const float* Wsrc = (c < 64) ? Wq : Wk;
        const int cc = c & 63;
        #pragma unroll
        for (int kk = 0; kk < 8; ++kk) {
            const int k = k0 + kg * 8 + kk;
            T[c][kg * 8 + kk] = f2bf(Wsrc[k * HSc + cc]);
        }
        __syncthreads();
        const int n = tid >> 1;
        const int h = tid & 1;
        const unsigned short* src = &T[n][h * 8];
        ushort4* dst = (ushort4*)(Wt + (size_t)n * Hc + k0 + h * 8);
        dst[0] = make_ushort4(src[0], src[1], src[2], src[3]);
        dst[1] = make_ushort4(src[4], src[5], src[6], src[7]);
    }
}

// MFMA GEMM: C[m][n] = x[m][:] . W[:][n], M=2048 N=128 K=768, bf16 in fp32 acc.
// Grid 256 x 256 thr (4 waves). Block bx: mb=bx>>1 (16-token tile), nh=bx&1
// (64-col half). Wave w owns n-tile nb = nh*64 + w*16. No LDS, no barriers:
// a/b fragments stream from L2 (xbf rows / Wt rows, 16B per lane per load),
// fully unrolled K-loop -> compiler vmcnt-pipelines freely.
// Layouts (m89/m91/m120): A[m=lane&15][k=quad*8+j]; B[k=quad*8+j][n=lane&15]
// loaded as Wt rows; D: col=lane&15, row=quad*4+reg.
__global__ __launch_bounds__(256) void gemm_kernel(
    const unsigned short* __restrict__ xbf, const unsigned short* __restrict__ Wt,
    const float* __restrict__ bq, const float* __restrict__ bk,
    float* __restrict__ qws, float* __restrict__ kws)
{
    const int bx   = blockIdx.x;
    const int mb   = bx >> 1;
    const int nh   = bx & 1;
    const int tid  = threadIdx.x;
    const int w    = tid >> 6;
    const int lane = tid & 63;
    const int l15  = lane & 15;
    const int quad = lane >> 4;

    const int m0 = mb * 16;
    const int nb = nh * 64 + w * 16;

    const unsigned short* ap = xbf + (size_t)(m0 + l15) * Hc + quad * 8;
    const unsigned short* bp = Wt  + (size_t)(nb + l15) * Hc + quad * 8;

    f32x4 acc = {0.f, 0.f, 0.f, 0.f};
    #pragma unroll
    for (int k0 = 0; k0 < Hc; k0 += 32) {
        const bf16x8 a = *(const bf16x8*)(ap + k0);
        const bf16x8 b = *(const bf16x8*)(bp + k0);
        acc = __builtin_amdgcn_mfma_f32_16x16x32_bf16(a, b, acc, 0, 0, 0);
    }

    const int  gn   = nb + l15;
    const bool isq  = (gn < 64);          // wave-uniform (nb mult of 16)
    const int  col  = gn & 63;
    const float bias = isq ? bq[col] : bk[col];
    float* dst = isq ? qws : kws;
    #pragma unroll
    for (int r = 0; r < 4; ++r) {
        const int tok = m0 + quad * 4 + r;
        dst[(size_t)tok * HSc + col] = acc[r] + bias;
    }
}

// A/E projections: A[t] = q@Wb[0:64]; E[t] = q@Wb[128:192] + k@(Wb[64:128]+Wb[192:256]) + bb.
// Grid 256 x 256 thr; 8 tokens/block; Wb staged in LDS (16 KB).
__global__ __launch_bounds__(256) void ae_kernel(
    const float* __restrict__ qws, const float* __restrict__ kws,
    const float* __restrict__ Wb, const float* __restrict__ bb,
    float* __restrict__ Aws, float* __restrict__ Ews)
{
    __shared__ float lWb[256 * OUTc];     // 16 KB
    __shared__ float lqk[8][128];
    const int tid = threadIdx.x;
    const int tok_base = blockIdx.x * 8;
    #pragma unroll
    for (int i = 0; i < 16; ++i) lWb[tid + i * 256] = Wb[tid + i * 256];
    for (int i = tid; i < 8 * 128; i += 256) {
        const int t = i >> 7, c = i & 127;
        lqk[t][c] = (c < 64) ? qws[(size_t)(tok_base + t) * HSc + c]
                             : kws[(size_t)(tok_base + t) * HSc + (c - 64)];
    }
    __syncthreads();
    const int t = tid >> 5;
    const int c = tid & 31;
    const int tok = tok_base + t;
    const float* row = lqk[t];
    if (c < 16) {
        float a = 0.f;
        #pragma unroll 8
        for (int h = 0; h < 64; ++h) a += row[h] * lWb[h * OUTc + c];
        Aws[(size_t)tok * OUTc + c] = a;
    } else {
        const int o = c - 16;
        float ev = bb[o];
        #pragma unroll 8
        for (int h = 0; h < 64; ++h) {
            ev += row[h]      * lWb[(128 + h) * OUTc + o];
            ev += row[64 + h] * (lWb[(64 + h) * OUTc + o] + lWb[(192 + h) * OUTc + o]);
        }
        Ews[(size_t)tok * OUTc + o] = ev;
    }
}

// Pair kernel (R6 tiled): Grid (8, 32, 4): x = e-tile (64 e's),
// y = s-tile (16 s's), z = batch. Tiles below diagonal exit early.
// q/A in LDS; k row + E chunk register-resident across 16 s-iterations.
__global__ __launch_bounds__(256) void pair_kernel(
    const float* __restrict__ qws, const float* __restrict__ kws,
    const float* __restrict__ Aws, const float* __restrict__ Ews,
    float* __restrict__ out)
{
    const int j = blockIdx.x;
    const int i = blockIdx.y;
    const int b = blockIdx.z;
    if (j < (i >> 2)) return;

    __shared__ alignas(16) float q_tile[16][64];
    __shared__ alignas(16) float A_tile[16][16];

    const int tid = threadIdx.x;
    const int s0 = i * 16;
    const int e0 = j * 64;

    {
        const int r = tid >> 4, c4 = tid & 15;
        ((float4*)q_tile[r])[c4] =
            ((const float4*)(qws + ((size_t)b * Lc + s0 + r) * HSc))[c4];
        if (tid < 64) {
            const int ra = tid >> 2, ca = tid & 3;
            ((float4*)A_tile[ra])[ca] =
                ((const float4*)(Aws + ((size_t)b * Lc + s0 + ra) * OUTc))[ca];
        }
    }
    __syncthreads();

    const int g = tid >> 2;
    const int l = tid & 3;
    const int e = e0 + g;

    const float4* kk = (const float4*)(kws + ((size_t)b * Lc + e) * HSc);
    const float4 kv0 = kk[l];
    const float4 kv1 = kk[4 + l];
    const float4 kv2 = kk[8 + l];
    const float4 kv3 = kk[12 + l];
    const float4 ev  = ((const float4*)(Ews + ((size_t)b * Lc + e) * OUTc))[l];

    float* ob = out + (size_t)b * Pc * OUTc;

    #pragma unroll 8
    for (int sl = 0; sl < 16; ++sl) {
        const int s = s0 + sl;
        const float4* qq = (const float4*)q_tile[sl];
        const float4 qv0 = qq[l];
        const float4 qv1 = qq[4 + l];
        const float4 qv2 = qq[8 + l];
        const float4 qv3 = qq[12 + l];

        float sc = qv0.x * kv0.x + qv0.y * kv0.y + qv0.z * kv0.z + qv0.w * kv0.w
                 + qv1.x * kv1.x + qv1.y * kv1.y + qv1.z * kv1.z + qv1.w * kv1.w
                 + qv2.x * kv2.x + qv2.y * kv2.y + qv2.z * kv2.z + qv2.w * kv2.w
                 + qv3.x * kv3.x + qv3.y * kv3.y + qv3.z * kv3.z + qv3.w * kv3.w;
        sc += __shfl_xor(sc, 1);
        sc += __shfl_xor(sc, 2);

        if (e >= s) {
            const float4 av = ((const float4*)A_tile[sl])[l];
            const int row = s * (2 * Lc + 1 - s) / 2 + (e - s);
            floatx4 r;
            r.x = av.x + ev.x + sc;
            r.y = av.y + ev.y + sc;
            r.z = av.z + ev.z + sc;
            r.w = av.w + ev.w + sc;
            __builtin_nontemporal_store(r, (floatx4*)(ob + (size_t)row * OUTc) + l);
        }
    }
}

extern "C" void kernel_launch(void* const* d_in, const int* in_sizes, int n_in,
                              void* d_out, int out_size, void* d_ws, size_t ws_size,
                              hipStream_t stream) {
    const float* x  = (const float*)d_in[0];
    const float* Wq = (const float*)d_in[1];
    const float* bq = (const float*)d_in[2];
    const float* Wk = (const float*)d_in[3];
    const float* bk = (const float*)d_in[4];
    const float* Wb = (const float*)d_in[5];
    const float* bb = (const float*)d_in[6];

    float* ws  = (float*)d_ws;
    float* qws = ws;
    float* kws = ws + 131072;
    float* Aws = ws + 262144;
    float* Ews = ws + 294912;
    unsigned short* xbf = (unsigned short*)(ws + 327680);
    unsigned short* Wt  = xbf + (size_t)NTOK * Hc;

    prep_kernel<<<dim3(560), dim3(256), 0, stream>>>(x, Wq, Wk, xbf, Wt);
    gemm_kernel<<<dim3(256), dim3(256), 0, stream>>>(xbf, Wt, bq, bk, qws, kws);
    ae_kernel<<<dim3(256), dim3(256), 0, stream>>>(qws, kws, Wb, bb, Aws, Ews);
    pair_kernel<<<dim3(8, 32, 4), dim3(256), 0, stream>>>(
        qws, kws, Aws, Ews, (float*)d_out);
}